// Round 7
// baseline (342.524 us; speedup 1.0000x reference)
//
#include <hip/hip_runtime.h>
#include <hip/hip_fp16.h>
#include <hip/hip_cooperative_groups.h>

namespace cg = cooperative_groups;

#define N_ITEMS 100000
#define HID 128
#define NNZ_T 1600000
#define GEMM_TILES 1563            // ceil(100000/64)
#define MAX_BLOCKS 2048

typedef unsigned short ushort_t;
typedef unsigned int uint_t;
typedef short bf16x8 __attribute__((ext_vector_type(8)));
typedef float f32x4 __attribute__((ext_vector_type(4)));

static __device__ __forceinline__ ushort_t f32_to_bf16(float f) {
    uint_t u = __float_as_uint(f);
    uint_t r = (u + 0x7FFFu + ((u >> 16) & 1u)) >> 16;   // RNE
    return (ushort_t)r;
}

// Single cooperative kernel (kills ~2 graph nodes' worth of fixed overhead):
//   P0: row_ptr binary searches (grid-strided; only low blocks have work)
//   P1: W f32->bf16 into LDS, XOR-swizzled (per block; proven r5 path)
//   P2: GEMM tiles grid-strided (frozen r5 MFMA body, bit-identical numerics)
//   -- grid.sync() --
//   P3: spmm, FROZEN r5 body (1 row/wave, 4 quad-gathers in flight, fp16 acc),
//       grid-strided so each block's 4 waves take 4 consecutive rows per step.
// r3's cooperative attempt spilled (VGPR capped 64 by launch_bounds(256,4):
// WRITE_SIZE showed +67MB scratch). No min-wave cap here -> no spill expected.
__global__ __launch_bounds__(256) void gcn_fused(
    const float* __restrict__ X, const int* __restrict__ rows,
    const int* __restrict__ cols, const float* __restrict__ vals,
    const float* __restrict__ W, const float* __restrict__ bias,
    ushort_t* __restrict__ S, int* __restrict__ row_ptr,
    float* __restrict__ out, int nblocks) {

    const int tid = threadIdx.x;
    const int lane = tid & 63;
    const int wave = tid >> 6;

    // ---- P0: row_ptr ----
    for (int r = blockIdx.x * 256 + tid; r <= N_ITEMS; r += nblocks * 256) {
        int lo = 0, hi = NNZ_T;
        while (lo < hi) {                    // lower_bound(rows, r), rows sorted
            int mid = (lo + hi) >> 1;
            if (rows[mid] < r) lo = mid + 1; else hi = mid;
        }
        row_ptr[r] = lo;
    }

    // ---- P1: stage W into LDS (phys = logical ^ ((row&7)<<3)) ----
    __shared__ ushort_t Wl[HID * HID];       // 32 KB bf16
    {
        const float4* Wf = (const float4*)W;
#pragma unroll
        for (int j = 0; j < 8; ++j) {
            const int gblk = j * 256 + tid;  // 16B granule id, 0..2047
            float4 w0 = Wf[gblk * 2];
            float4 w1 = Wf[gblk * 2 + 1];
            bf16x8 v;
            v[0] = (short)f32_to_bf16(w0.x); v[1] = (short)f32_to_bf16(w0.y);
            v[2] = (short)f32_to_bf16(w0.z); v[3] = (short)f32_to_bf16(w0.w);
            v[4] = (short)f32_to_bf16(w1.x); v[5] = (short)f32_to_bf16(w1.y);
            v[6] = (short)f32_to_bf16(w1.z); v[7] = (short)f32_to_bf16(w1.w);
            const int ps = (gblk * 8) ^ (((gblk >> 4) & 7) << 3);
            *(bf16x8*)&Wl[ps] = v;
        }
    }
    __syncthreads();

    // ---- P2: GEMM tiles ----
    const int m = lane & 15;
    const int q = lane >> 4;
    const int swz = (m & 7) << 3;            // row&7 == m&7 for row = nt*16+m
    for (int tile = blockIdx.x; tile < GEMM_TILES; tile += nblocks) {
        const int row0 = tile * 64 + wave * 16;
        int arow = row0 + m;
        if (arow >= N_ITEMS) arow = N_ITEMS - 1;   // clamp (stores guarded)

        f32x4 acc[8] = {};
#pragma unroll
        for (int kb = 0; kb < 4; ++kb) {
            const int k0 = kb * 32 + q * 8;
            float4 a0 = *(const float4*)&X[(size_t)arow * HID + k0];
            float4 a1 = *(const float4*)&X[(size_t)arow * HID + k0 + 4];
            bf16x8 xf;
            xf[0] = (short)f32_to_bf16(a0.x); xf[1] = (short)f32_to_bf16(a0.y);
            xf[2] = (short)f32_to_bf16(a0.z); xf[3] = (short)f32_to_bf16(a0.w);
            xf[4] = (short)f32_to_bf16(a1.x); xf[5] = (short)f32_to_bf16(a1.y);
            xf[6] = (short)f32_to_bf16(a1.z); xf[7] = (short)f32_to_bf16(a1.w);
#pragma unroll
            for (int nt = 0; nt < 8; ++nt) {
                const bf16x8 wf = *(const bf16x8*)&Wl[((nt * 16 + m) * HID + k0) ^ swz];
                acc[nt] = __builtin_amdgcn_mfma_f32_16x16x32_bf16(wf, xf, acc[nt], 0, 0, 0);
            }
        }

        const int srow = row0 + m;
        const bool ok = srow < N_ITEMS;
#pragma unroll
        for (int nt = 0; nt < 8; ++nt) {
            const int c0 = nt * 16 + q * 4;  // 4 consecutive out cols
            float4 bv = *(const float4*)&bias[c0];
            ushort_t h0 = __half_as_ushort(__float2half(acc[nt][0] + bv.x));
            ushort_t h1 = __half_as_ushort(__float2half(acc[nt][1] + bv.y));
            ushort_t h2 = __half_as_ushort(__float2half(acc[nt][2] + bv.z));
            ushort_t h3 = __half_as_ushort(__float2half(acc[nt][3] + bv.w));
            uint2 pk;
            pk.x = (uint_t)h0 | ((uint_t)h1 << 16);
            pk.y = (uint_t)h2 | ((uint_t)h3 << 16);
            if (ok) *(uint2*)&S[(size_t)srow * HID + c0] = pk;
        }
    }

    cg::this_grid().sync();

    // ---- P3: spmm — FROZEN r5 body, grid-strided ----
    const int g = lane >> 4;                 // edge slot within a quad (0..3)
    const int l = lane & 15;                 // column octet: cols 8*l .. 8*l+7

    for (int r = blockIdx.x * 4 + wave; r < N_ITEMS; r += nblocks * 4) {
        int pa = row_ptr[r];
        const int pE = row_ptr[r + 1];

        __half2 acc[4];
#pragma unroll
        for (int j = 0; j < 4; ++j) acc[j] = __float2half2_rn(0.f);

        while (pa < pE) {
            const int idx  = pa + l;
            const int cidx = min(idx, pE - 1);        // pE > pa >= 0 here
            const int c_l  = cols[cidx];
            const float v_l = (idx < pE) ? vals[cidx] : 0.f;

            uint4 u[4];
            float vv[4];
#pragma unroll
            for (int t = 0; t < 4; ++t) {             // 4 quad-gathers in flight
                const int s = 4 * t + g;              // slot index 0..15
                const int ct = __shfl(c_l, s, 64);
                vv[t] = __shfl(v_l, s, 64);
                u[t] = *(const uint4*)&S[(size_t)ct * HID + 8 * l];
            }
#pragma unroll
            for (int t = 0; t < 4; ++t) {
                const __half2 w = __float2half2_rn(vv[t]);
                acc[0] = __hfma2(w, *(const __half2*)&u[t].x, acc[0]);
                acc[1] = __hfma2(w, *(const __half2*)&u[t].y, acc[1]);
                acc[2] = __hfma2(w, *(const __half2*)&u[t].z, acc[2]);
                acc[3] = __hfma2(w, *(const __half2*)&u[t].w, acc[3]);
            }
            pa += 16;
        }

        float f[8];
#pragma unroll
        for (int j = 0; j < 4; ++j) {
            f[2 * j] = __low2float(acc[j]);  f[2 * j + 1] = __high2float(acc[j]);
        }
#pragma unroll
        for (int e = 0; e < 8; ++e) {
            f[e] += __shfl_xor(f[e], 16, 64);
            f[e] += __shfl_xor(f[e], 32, 64);
        }
        if (g == 0) {                        // lanes 0-15 store the 512B row
            float* p = &out[(size_t)r * HID + 8 * l];
            *(float4*)p       = make_float4(f[0], f[1], f[2], f[3]);
            *(float4*)(p + 4) = make_float4(f[4], f[5], f[6], f[7]);
        }
    }
}

extern "C" void kernel_launch(void* const* d_in, const int* in_sizes, int n_in,
                              void* d_out, int out_size, void* d_ws, size_t ws_size,
                              hipStream_t stream) {
    const float* X    = (const float*)d_in[0];
    const int*   rows = (const int*)  d_in[1];
    const int*   cols = (const int*)  d_in[2];
    const float* vals = (const float*)d_in[3];
    const float* W    = (const float*)d_in[4];
    const float* bias = (const float*)d_in[5];
    float* out = (float*)d_out;

    ushort_t* S       = (ushort_t*)d_ws;                    // 25.6 MB (fp16)
    int*      row_ptr = (int*)(S + (size_t)N_ITEMS * HID);  // 400 KB

    static int nblocks = 0;                  // host-side queries, capture-safe (r3)
    if (nblocks == 0) {
        int per_cu = 0;
        hipOccupancyMaxActiveBlocksPerMultiprocessor(
            &per_cu, reinterpret_cast<const void*>(gcn_fused), 256, 0);
        int num_cu = 256;
        hipDeviceProp_t prop;
        if (hipGetDeviceProperties(&prop, 0) == hipSuccess && prop.multiProcessorCount > 0)
            num_cu = prop.multiProcessorCount;
        nblocks = (per_cu > 0 ? per_cu : 1) * num_cu;
        if (nblocks > MAX_BLOCKS) nblocks = MAX_BLOCKS;
        if (nblocks < 256) nblocks = 256;
    }

    void* args[] = {(void*)&X, (void*)&rows, (void*)&cols, (void*)&vals,
                    (void*)&W, (void*)&bias, (void*)&S, (void*)&row_ptr,
                    (void*)&out, (void*)&nblocks};
    hipLaunchCooperativeKernel(reinterpret_cast<void*>(gcn_fused),
                               dim3(nblocks), dim3(256), args, 0, stream);
}

// Round 8
// 190.753 us; speedup vs baseline: 1.7956x; 1.7956x over previous
//
#include <hip/hip_runtime.h>
#include <hip/hip_fp16.h>

#define N_ITEMS 100000
#define HID 128
#define NNZ_T 1600000
#define GEMM_TILES 1563            // ceil(100000/64)
#define GEMM_BLOCKS 391            // x4 tiles each = 1564 tiles (last guarded)
#define RP_BLOCKS 391              // binary-search blocks, placed LAST (backfill)
#define SPMM_BLOCKS 25000          // FROZEN r5: 1 row per wave, 4 waves/block

typedef unsigned short ushort_t;
typedef unsigned int uint_t;
typedef short bf16x8 __attribute__((ext_vector_type(8)));
typedef float f32x4 __attribute__((ext_vector_type(4)));

static __device__ __forceinline__ ushort_t f32_to_bf16(float f) {
    uint_t u = __float_as_uint(f);
    uint_t r = (u + 0x7FFFu + ((u >> 16) & 1u)) >> 16;   // RNE
    return (ushort_t)r;
}

// === K1: blocks [0,GEMM_BLOCKS) each run EXACTLY 4 GEMM tiles (compile-time
// trip count -> compiler software-pipelines X loads across tiles; W staging
// amortized over 4 tiles instead of 2). Blocks [GEMM_BLOCKS..+RP_BLOCKS) do
// row_ptr binary searches, placed last to backfill the GEMM tail.
__global__ __launch_bounds__(256) void prep_gemm(
    const float* __restrict__ X, const float* __restrict__ W,
    const float* __restrict__ bias, const int* __restrict__ rows,
    ushort_t* __restrict__ S, int* __restrict__ row_ptr) {
    if (blockIdx.x >= GEMM_BLOCKS) {
        int r = (blockIdx.x - GEMM_BLOCKS) * 256 + threadIdx.x;
        if (r > N_ITEMS) return;
        int lo = 0, hi = NNZ_T;
        while (lo < hi) {                       // lower_bound(rows, r), rows sorted
            int mid = (lo + hi) >> 1;
            if (rows[mid] < r) lo = mid + 1; else hi = mid;
        }
        row_ptr[r] = lo;
        return;
    }

    __shared__ ushort_t Wl[HID * HID];          // 32 KB bf16, XOR-swizzled
    {
        const int t = threadIdx.x;
        const float4* Wf = (const float4*)W;
#pragma unroll
        for (int j = 0; j < 8; ++j) {
            const int gblk = j * 256 + t;       // 16B granule id, 0..2047
            float4 w0 = Wf[gblk * 2];
            float4 w1 = Wf[gblk * 2 + 1];
            bf16x8 v;
            v[0] = (short)f32_to_bf16(w0.x); v[1] = (short)f32_to_bf16(w0.y);
            v[2] = (short)f32_to_bf16(w0.z); v[3] = (short)f32_to_bf16(w0.w);
            v[4] = (short)f32_to_bf16(w1.x); v[5] = (short)f32_to_bf16(w1.y);
            v[6] = (short)f32_to_bf16(w1.z); v[7] = (short)f32_to_bf16(w1.w);
            const int ps = (gblk * 8) ^ (((gblk >> 4) & 7) << 3);  // phys short idx
            *(bf16x8*)&Wl[ps] = v;
        }
    }
    __syncthreads();

    const int lane = threadIdx.x & 63;
    const int wave = threadIdx.x >> 6;
    const int m = lane & 15;
    const int q = lane >> 4;
    const int swz = (m & 7) << 3;               // row&7 == m&7 for row = nt*16+m

#pragma unroll
    for (int it = 0; it < 4; ++it) {            // exactly 4 tiles per block
        const int tile = blockIdx.x + it * GEMM_BLOCKS;   // < 1564
        const int row0 = tile * 64 + wave * 16;
        int arow = row0 + m;
        if (arow >= N_ITEMS) arow = N_ITEMS - 1;   // clamp (stores guarded)

        f32x4 acc[8] = {};
#pragma unroll
        for (int kb = 0; kb < 4; ++kb) {
            const int k0 = kb * 32 + q * 8;
            float4 a0 = *(const float4*)&X[(size_t)arow * HID + k0];
            float4 a1 = *(const float4*)&X[(size_t)arow * HID + k0 + 4];
            bf16x8 xf;
            xf[0] = (short)f32_to_bf16(a0.x); xf[1] = (short)f32_to_bf16(a0.y);
            xf[2] = (short)f32_to_bf16(a0.z); xf[3] = (short)f32_to_bf16(a0.w);
            xf[4] = (short)f32_to_bf16(a1.x); xf[5] = (short)f32_to_bf16(a1.y);
            xf[6] = (short)f32_to_bf16(a1.z); xf[7] = (short)f32_to_bf16(a1.w);
#pragma unroll
            for (int nt = 0; nt < 8; ++nt) {
                const bf16x8 wf = *(const bf16x8*)&Wl[((nt * 16 + m) * HID + k0) ^ swz];
                acc[nt] = __builtin_amdgcn_mfma_f32_16x16x32_bf16(wf, xf, acc[nt], 0, 0, 0);
            }
        }

        const int srow = row0 + m;
        const bool ok = srow < N_ITEMS;
#pragma unroll
        for (int nt = 0; nt < 8; ++nt) {
            const int c0 = nt * 16 + q * 4;     // 4 consecutive out cols
            float4 bv = *(const float4*)&bias[c0];
            ushort_t h0 = __half_as_ushort(__float2half(acc[nt][0] + bv.x));
            ushort_t h1 = __half_as_ushort(__float2half(acc[nt][1] + bv.y));
            ushort_t h2 = __half_as_ushort(__float2half(acc[nt][2] + bv.z));
            ushort_t h3 = __half_as_ushort(__float2half(acc[nt][3] + bv.w));
            uint2 pk;
            pk.x = (uint_t)h0 | ((uint_t)h1 << 16);
            pk.y = (uint_t)h2 | ((uint_t)h3 << 16);
            if (ok) *(uint2*)&S[(size_t)srow * HID + c0] = pk;
        }
    }
}

// === K2: FROZEN round-5 spmm (measured 60.8us, ~3.9 TB/s local roofline) ===
__global__ __launch_bounds__(256) void spmm_csr(
    const int* __restrict__ cols, const float* __restrict__ vals,
    const int* __restrict__ row_ptr, const ushort_t* __restrict__ S,
    float* __restrict__ out) {
    const int lane = threadIdx.x & 63;
    const int r = blockIdx.x * 4 + (threadIdx.x >> 6);    // one row per wave
    if (r >= N_ITEMS) return;

    const int g = lane >> 4;                // edge slot within a quad (0..3)
    const int l = lane & 15;                // column octet: cols 8*l .. 8*l+7

    int pa = row_ptr[r];
    const int pE = row_ptr[r + 1];

    __half2 acc[4];
#pragma unroll
    for (int j = 0; j < 4; ++j) acc[j] = __float2half2_rn(0.f);

    while (pa < pE) {
        // lanes 0-15 load 16 contiguous (col,val); other groups duplicate (1 line)
        const int idx  = pa + l;
        const int cidx = min(idx, pE - 1);            // pE > pa >= 0 here
        const int c_l  = cols[cidx];
        const float v_l = (idx < pE) ? vals[cidx] : 0.f;

        uint4 u[4];
        float vv[4];
#pragma unroll
        for (int t = 0; t < 4; ++t) {                 // 4 quad-gathers in flight
            const int s = 4 * t + g;                  // slot index 0..15
            const int ct = __shfl(c_l, s, 64);
            vv[t] = __shfl(v_l, s, 64);
            u[t] = *(const uint4*)&S[(size_t)ct * HID + 8 * l];
        }
#pragma unroll
        for (int t = 0; t < 4; ++t) {
            const __half2 w = __float2half2_rn(vv[t]);
            acc[0] = __hfma2(w, *(const __half2*)&u[t].x, acc[0]);
            acc[1] = __hfma2(w, *(const __half2*)&u[t].y, acc[1]);
            acc[2] = __hfma2(w, *(const __half2*)&u[t].z, acc[2]);
            acc[3] = __hfma2(w, *(const __half2*)&u[t].w, acc[3]);
        }
        pa += 16;
    }

    // unpack to f32; reduce over the 4 edge-groups (lanes l, l+16, l+32, l+48)
    float f[8];
#pragma unroll
    for (int j = 0; j < 4; ++j) {
        f[2 * j] = __low2float(acc[j]);  f[2 * j + 1] = __high2float(acc[j]);
    }
#pragma unroll
    for (int e = 0; e < 8; ++e) {
        f[e] += __shfl_xor(f[e], 16, 64);
        f[e] += __shfl_xor(f[e], 32, 64);
    }
    if (g == 0) {                           // lanes 0-15 store the 512B row
        float* p = &out[(size_t)r * HID + 8 * l];
        *(float4*)p       = make_float4(f[0], f[1], f[2], f[3]);
        *(float4*)(p + 4) = make_float4(f[4], f[5], f[6], f[7]);
    }
}

extern "C" void kernel_launch(void* const* d_in, const int* in_sizes, int n_in,
                              void* d_out, int out_size, void* d_ws, size_t ws_size,
                              hipStream_t stream) {
    const float* X    = (const float*)d_in[0];
    const int*   rows = (const int*)  d_in[1];
    const int*   cols = (const int*)  d_in[2];
    const float* vals = (const float*)d_in[3];
    const float* W    = (const float*)d_in[4];
    const float* bias = (const float*)d_in[5];
    float* out = (float*)d_out;

    ushort_t* S       = (ushort_t*)d_ws;                    // 25.6 MB (fp16)
    int*      row_ptr = (int*)(S + (size_t)N_ITEMS * HID);  // 400 KB

    prep_gemm<<<GEMM_BLOCKS + RP_BLOCKS, 256, 0, stream>>>(X, W, bias, rows, S, row_ptr);
    spmm_csr<<<SPMM_BLOCKS, 256, 0, stream>>>(cols, vals, row_ptr, S, out);
}

// Round 9
// 189.820 us; speedup vs baseline: 1.8045x; 1.0049x over previous
//
#include <hip/hip_runtime.h>
#include <hip/hip_fp16.h>

#define N_ITEMS 100000
#define HID 128
#define NNZ_T 1600000
#define GEMM_TILES 1563            // ceil(100000/64)
#define GEMM_BLOCKS 781            // 2 tiles per block: W staged once per 2 tiles
#define RP_BLOCKS 391              // binary-search blocks, placed LAST (backfill)
#define SPMM_BLOCKS 25000          // 1 row per wave, 4 waves/block

typedef unsigned short ushort_t;
typedef unsigned int uint_t;
typedef short bf16x8 __attribute__((ext_vector_type(8)));
typedef float f32x4 __attribute__((ext_vector_type(4)));

static __device__ __forceinline__ ushort_t f32_to_bf16(float f) {
    uint_t u = __float_as_uint(f);
    uint_t r = (u + 0x7FFFu + ((u >> 16) & 1u)) >> 16;   // RNE
    return (ushort_t)r;
}

// === K1: blocks [0,GEMM_BLOCKS) grid-stride the GEMM tiles (W staged in LDS
// once per block, XOR-swizzled); blocks [GEMM_BLOCKS..+RP_BLOCKS) do the
// row_ptr binary searches — placed LAST so they backfill the GEMM tail
// instead of delaying GEMM dispatch. Plain (cached) loads everywhere (r4:
// nontemporal regressed both kernels).
__global__ __launch_bounds__(256) void prep_gemm(
    const float* __restrict__ X, const float* __restrict__ W,
    const float* __restrict__ bias, const int* __restrict__ rows,
    ushort_t* __restrict__ S, int* __restrict__ row_ptr) {
    if (blockIdx.x >= GEMM_BLOCKS) {
        int r = (blockIdx.x - GEMM_BLOCKS) * 256 + threadIdx.x;
        if (r > N_ITEMS) return;
        int lo = 0, hi = NNZ_T;
        while (lo < hi) {                       // lower_bound(rows, r), rows sorted
            int mid = (lo + hi) >> 1;
            if (rows[mid] < r) lo = mid + 1; else hi = mid;
        }
        row_ptr[r] = lo;
        return;
    }

    __shared__ ushort_t Wl[HID * HID];          // 32 KB bf16, XOR-swizzled
    {
        const int t = threadIdx.x;
        const float4* Wf = (const float4*)W;
#pragma unroll
        for (int j = 0; j < 8; ++j) {
            const int gblk = j * 256 + t;       // 16B granule id, 0..2047
            float4 w0 = Wf[gblk * 2];
            float4 w1 = Wf[gblk * 2 + 1];
            bf16x8 v;
            v[0] = (short)f32_to_bf16(w0.x); v[1] = (short)f32_to_bf16(w0.y);
            v[2] = (short)f32_to_bf16(w0.z); v[3] = (short)f32_to_bf16(w0.w);
            v[4] = (short)f32_to_bf16(w1.x); v[5] = (short)f32_to_bf16(w1.y);
            v[6] = (short)f32_to_bf16(w1.z); v[7] = (short)f32_to_bf16(w1.w);
            const int ps = (gblk * 8) ^ (((gblk >> 4) & 7) << 3);  // phys short idx
            *(bf16x8*)&Wl[ps] = v;
        }
    }
    __syncthreads();

    const int lane = threadIdx.x & 63;
    const int wave = threadIdx.x >> 6;
    const int m = lane & 15;
    const int q = lane >> 4;
    const int swz = (m & 7) << 3;               // row&7 == m&7 for row = nt*16+m

    for (int tile = blockIdx.x; tile < GEMM_TILES; tile += GEMM_BLOCKS) {
        const int row0 = tile * 64 + wave * 16;
        int arow = row0 + m;
        if (arow >= N_ITEMS) arow = N_ITEMS - 1;   // clamp (stores guarded)

        f32x4 acc[8] = {};
#pragma unroll
        for (int kb = 0; kb < 4; ++kb) {
            const int k0 = kb * 32 + q * 8;
            float4 a0 = *(const float4*)&X[(size_t)arow * HID + k0];
            float4 a1 = *(const float4*)&X[(size_t)arow * HID + k0 + 4];
            bf16x8 xf;
            xf[0] = (short)f32_to_bf16(a0.x); xf[1] = (short)f32_to_bf16(a0.y);
            xf[2] = (short)f32_to_bf16(a0.z); xf[3] = (short)f32_to_bf16(a0.w);
            xf[4] = (short)f32_to_bf16(a1.x); xf[5] = (short)f32_to_bf16(a1.y);
            xf[6] = (short)f32_to_bf16(a1.z); xf[7] = (short)f32_to_bf16(a1.w);
#pragma unroll
            for (int nt = 0; nt < 8; ++nt) {
                const bf16x8 wf = *(const bf16x8*)&Wl[((nt * 16 + m) * HID + k0) ^ swz];
                acc[nt] = __builtin_amdgcn_mfma_f32_16x16x32_bf16(wf, xf, acc[nt], 0, 0, 0);
            }
        }

        const int srow = row0 + m;
        const bool ok = srow < N_ITEMS;
#pragma unroll
        for (int nt = 0; nt < 8; ++nt) {
            const int c0 = nt * 16 + q * 4;     // 4 consecutive out cols
            float4 bv = *(const float4*)&bias[c0];
            ushort_t h0 = __half_as_ushort(__float2half(acc[nt][0] + bv.x));
            ushort_t h1 = __half_as_ushort(__float2half(acc[nt][1] + bv.y));
            ushort_t h2 = __half_as_ushort(__float2half(acc[nt][2] + bv.z));
            ushort_t h3 = __half_as_ushort(__float2half(acc[nt][3] + bv.w));
            uint2 pk;
            pk.x = (uint_t)h0 | ((uint_t)h1 << 16);
            pk.y = (uint_t)h2 | ((uint_t)h3 << 16);
            if (ok) *(uint2*)&S[(size_t)srow * HID + c0] = pk;
        }
    }
}

// === K2: FROZEN round-5 spmm (measured 60.8us, ~3.9 TB/s local roofline) ===
__global__ __launch_bounds__(256) void spmm_csr(
    const int* __restrict__ cols, const float* __restrict__ vals,
    const int* __restrict__ row_ptr, const ushort_t* __restrict__ S,
    float* __restrict__ out) {
    const int lane = threadIdx.x & 63;
    const int r = blockIdx.x * 4 + (threadIdx.x >> 6);    // one row per wave
    if (r >= N_ITEMS) return;

    const int g = lane >> 4;                // edge slot within a quad (0..3)
    const int l = lane & 15;                // column octet: cols 8*l .. 8*l+7

    int pa = row_ptr[r];
    const int pE = row_ptr[r + 1];

    __half2 acc[4];
#pragma unroll
    for (int j = 0; j < 4; ++j) acc[j] = __float2half2_rn(0.f);

    while (pa < pE) {
        // lanes 0-15 load 16 contiguous (col,val); other groups duplicate (1 line)
        const int idx  = pa + l;
        const int cidx = min(idx, pE - 1);            // pE > pa >= 0 here
        const int c_l  = cols[cidx];
        const float v_l = (idx < pE) ? vals[cidx] : 0.f;

        uint4 u[4];
        float vv[4];
#pragma unroll
        for (int t = 0; t < 4; ++t) {                 // 4 quad-gathers in flight
            const int s = 4 * t + g;                  // slot index 0..15
            const int ct = __shfl(c_l, s, 64);
            vv[t] = __shfl(v_l, s, 64);
            u[t] = *(const uint4*)&S[(size_t)ct * HID + 8 * l];
        }
#pragma unroll
        for (int t = 0; t < 4; ++t) {
            const __half2 w = __float2half2_rn(vv[t]);
            acc[0] = __hfma2(w, *(const __half2*)&u[t].x, acc[0]);
            acc[1] = __hfma2(w, *(const __half2*)&u[t].y, acc[1]);
            acc[2] = __hfma2(w, *(const __half2*)&u[t].z, acc[2]);
            acc[3] = __hfma2(w, *(const __half2*)&u[t].w, acc[3]);
        }
        pa += 16;
    }

    // unpack to f32; reduce over the 4 edge-groups (lanes l, l+16, l+32, l+48)
    float f[8];
#pragma unroll
    for (int j = 0; j < 4; ++j) {
        f[2 * j] = __low2float(acc[j]);  f[2 * j + 1] = __high2float(acc[j]);
    }
#pragma unroll
    for (int e = 0; e < 8; ++e) {
        f[e] += __shfl_xor(f[e], 16, 64);
        f[e] += __shfl_xor(f[e], 32, 64);
    }
    if (g == 0) {                           // lanes 0-15 store the 512B row
        float* p = &out[(size_t)r * HID + 8 * l];
        *(float4*)p       = make_float4(f[0], f[1], f[2], f[3]);
        *(float4*)(p + 4) = make_float4(f[4], f[5], f[6], f[7]);
    }
}

extern "C" void kernel_launch(void* const* d_in, const int* in_sizes, int n_in,
                              void* d_out, int out_size, void* d_ws, size_t ws_size,
                              hipStream_t stream) {
    const float* X    = (const float*)d_in[0];
    const int*   rows = (const int*)  d_in[1];
    const int*   cols = (const int*)  d_in[2];
    const float* vals = (const float*)d_in[3];
    const float* W    = (const float*)d_in[4];
    const float* bias = (const float*)d_in[5];
    float* out = (float*)d_out;

    ushort_t* S       = (ushort_t*)d_ws;                    // 25.6 MB (fp16)
    int*      row_ptr = (int*)(S + (size_t)N_ITEMS * HID);  // 400 KB

    prep_gemm<<<GEMM_BLOCKS + RP_BLOCKS, 256, 0, stream>>>(X, W, bias, rows, S, row_ptr);
    spmm_csr<<<SPMM_BLOCKS, 256, 0, stream>>>(cols, vals, row_ptr, S, out);
}